// Round 11
// baseline (285.985 us; speedup 1.0000x reference)
//
#include <hip/hip_runtime.h>
#include <math.h>

// Problem constants
#define Bn 2
#define Vn 6
#define Cn 96
#define Dn 48
#define Hn 48
#define Wn 48
#define THn 96
#define TWn 96
#define EPSf 1e-5f

// packetized geometry: 16B packets of 8 consecutive ci
#define PD 98
#define NCI8 12
// rz:  (((vb*PD+py)*NCI8 + ci8)*PD + px)*8 + e     (bf16, zero-padded halo)
// co1: (((vb*NCI8+co8)*9216 + n)*8 + e             (bf16)
// wAtP:(((tap*NCI8+ci8)*96 + co)*8 + e             (bf16)
// wCP: ((ci8*96 + co)*8 + e                        (bf16)

typedef __attribute__((ext_vector_type(8))) short s8v;   // 8 bf16
typedef __attribute__((ext_vector_type(4))) float f4v;   // MFMA acc
typedef __attribute__((ext_vector_type(2))) float f2v;   // packed fp32 pair

__device__ __forceinline__ unsigned short f2bf(float f) {
    unsigned int u = __builtin_bit_cast(unsigned int, f);
    u += 0x7FFFu + ((u >> 16) & 1u);          // RNE
    return (unsigned short)(u >> 16);
}
__device__ __forceinline__ float bf2f(unsigned short h) {
    unsigned int u = ((unsigned int)h) << 16;
    return __builtin_bit_cast(float, u);
}
__device__ __forceinline__ void unpack8(uint4 r, float* f) {
    unsigned int w[4] = {r.x, r.y, r.z, r.w};
#pragma unroll
    for (int j = 0; j < 8; ++j)
        f[j] = bf2f((unsigned short)((w[j >> 1] >> ((j & 1) * 16)) & 0xFFFFu));
}
// unpack a 16B packet into 4 float2 pairs: pair i = channels (2i, 2i+1)
__device__ __forceinline__ void unpack8p(uint4 r, f2v* p) {
    unsigned int w[4] = {r.x, r.y, r.z, r.w};
#pragma unroll
    for (int i = 0; i < 4; ++i) {
        f2v t;
        t.x = __builtin_bit_cast(float, w[i] << 16);
        t.y = __builtin_bit_cast(float, w[i] & 0xFFFF0000u);
        p[i] = t;
    }
}
__device__ __forceinline__ uint4 pack8(const unsigned short* o) {
    uint4 pk;
    pk.x = (unsigned int)o[0] | ((unsigned int)o[1] << 16);
    pk.y = (unsigned int)o[2] | ((unsigned int)o[3] << 16);
    pk.z = (unsigned int)o[4] | ((unsigned int)o[5] << 16);
    pk.w = (unsigned int)o[6] | ((unsigned int)o[7] << 16);
    return pk;
}

// Branchless exact-GELU: erf via Abramowitz-Stegun 7.1.26 (|err| < 1.5e-7).
__device__ __forceinline__ float gelu_f(float y) {
    float z = y * 0.70710678118654752f;
    float a = fabsf(z);
    float t = __builtin_amdgcn_rcpf(fmaf(0.3275911f, a, 1.0f));
    float e = __builtin_amdgcn_exp2f(-1.4426950408889634f * a * a);
    float p = t * fmaf(t, fmaf(t, fmaf(t, fmaf(t, 1.061405429f,
                                               -1.453152027f),
                                       1.421413741f),
                               -0.284496736f),
                       0.254829592f);
    float er = fmaf(-p, e, 1.0f);            // erf(|z|)
    er = copysignf(er, z);
    return 0.5f * y * (1.0f + er);
}

// ---------------------------------------------------------------------------
// K0: merged tokens fp32->bf16 + weight prep. blk<10368: tok; else weights.
// ---------------------------------------------------------------------------
__global__ __launch_bounds__(256) void k_pre(const float* __restrict__ tokens,
                                             unsigned short* __restrict__ tokB,
                                             const float* __restrict__ w1,
                                             const float* __restrict__ w2,
                                             unsigned short* __restrict__ wAtP,
                                             unsigned short* __restrict__ wCP) {
    if (blockIdx.x < 10368) {
        int idx = blockIdx.x * 256 + threadIdx.x;      // 2,654,208 threads
        size_t base = (size_t)idx * 8;
        float4 f0 = *(const float4*)(tokens + base);
        float4 f1 = *(const float4*)(tokens + base + 4);
        unsigned short o[8] = {f2bf(f0.x), f2bf(f0.y), f2bf(f0.z), f2bf(f0.w),
                               f2bf(f1.x), f2bf(f1.y), f2bf(f1.z), f2bf(f1.w)};
        *(uint4*)(&tokB[base]) = pack8(o);
    } else {
        int i = (blockIdx.x - 10368) * 256 + threadIdx.x;
        if (i < 82944) {                       // 9*12*96*8
            int e = i & 7;
            int u = i >> 3;
            int co = u % 96;
            int u2 = u / 96;                   // tap*12 + ci8
            int ci8 = u2 % NCI8;
            int tap = u2 / NCI8;
            wAtP[i] = f2bf(w1[(co * 96 + ci8 * 8 + e) * 9 + tap]);
        } else if (i < 92160) {
            int j = i - 82944;
            int e = j & 7;
            int u = j >> 3;
            int co = u % 96;
            int ci8 = u / 96;
            wCP[j] = f2bf(w2[co * 96 + ci8 * 8 + e]);
        }
    }
}

// ---------------------------------------------------------------------------
// K1: projection; 32 CHANNELS (4 contiguous packets, 64B/tap) per thread so
// geometry+addressing amortizes 4x (k_feat9 was VALU-issue-bound at 80%).
// z split across wave quarters (lane bits 4-5); (b,y)-major site order +
// XCD-chunked swizzle (each XCD: 12 slices = 5.3 MB, L2-resident).
// 331,776 threads -> 1296 blocks. Geometry arithmetic identical to round 10.
// ---------------------------------------------------------------------------
__global__ __launch_bounds__(256) void k_feat10(const unsigned short* __restrict__ tokB,
                                                const float* __restrict__ angles,
                                                unsigned short* __restrict__ featP) {
    int gid = blockIdx.x;
    int xcd = gid & 7;
    int pos = gid >> 3;
    int vblk = xcd * 162 + pos;            // virtual block, (b,y)-major order
    int t = threadIdx.x;
    int l = t & 63;
    int h = l >> 4;                        // z-quarter 0..3
    int site = vblk * 64 + (t >> 6) * 16 + (l & 15);  // 0..82943
    int g = site % 3;                      // c32 group: packets 4g..4g+3
    int r = site / 3;
    int x = r % 48; r /= 48;
    int v = r % 6;  r /= 6;
    int y = r % 48;
    int b = r / 48;
    int vb = v * 2 + b;

    float th = angles[v];
    float ct = cosf(th), st = sinf(th);
    float xr = (float)x + 0.5f - 24.0f;
    float xterm = ct * xr + 23.5f;         // ix = st*zr + xterm
    float zterm = -st * xr + 23.5f;        // iz = ct*zr + zterm

    const char* tb = (const char*)tokB +
                     ((size_t)b * 10616832 + (size_t)y * 4608 + g * 32) * 2;

    f2v af[16];
#pragma unroll
    for (int i = 0; i < 16; ++i) af[i] = (f2v){0.f, 0.f};

#pragma unroll 2
    for (int k = 0; k < 12; ++k) {
        float zr = (float)(h * 12 + k) + 0.5f - 24.0f;
        float ix = fmaf(st, zr, xterm);
        float iz = fmaf(ct, zr, zterm);
        float x0f = floorf(ix), z0f = floorf(iz);
        float tx = ix - x0f, tz = iz - z0f;
        int x0 = (int)x0f, z0 = (int)z0f;
        float wx0 = (1.f - tx) * (((x0 >= 0) && (x0 < 48)) ? 1.f : 0.f);
        float wx1 = tx * (((x0 >= -1) && (x0 < 47)) ? 1.f : 0.f);
        float wz0 = (1.f - tz) * (((z0 >= 0) && (z0 < 48)) ? 1.f : 0.f);
        float wz1 = tz * (((z0 >= -1) && (z0 < 47)) ? 1.f : 0.f);
        int xi0 = min(max(x0, 0), 47), xi1 = min(max(x0 + 1, 0), 47);
        int zi0 = min(max(z0, 0), 47), zi1 = min(max(z0 + 1, 0), 47);
        int r0o = zi0 * 442368, r1o = zi1 * 442368;   // byte row offsets
        int c0o = xi0 * 192,    c1o = xi1 * 192;      // byte col offsets
        int o00 = r0o + c0o, o01 = r0o + c1o;
        int o10 = r1o + c0o, o11 = r1o + c1o;

        float w00 = wz0 * wx0, w01 = wz0 * wx1;
        float w10 = wz1 * wx0, w11 = wz1 * wx1;
        f2v v00 = (f2v){w00, w00}, v01 = (f2v){w01, w01};
        f2v v10 = (f2v){w10, w10}, v11 = (f2v){w11, w11};

#pragma unroll
        for (int pp = 0; pp < 4; ++pp) {
            int po = pp * 16;
            uint4 r00 = *(const uint4*)(tb + (o00 + po));
            uint4 r01 = *(const uint4*)(tb + (o01 + po));
            uint4 r10 = *(const uint4*)(tb + (o10 + po));
            uint4 r11 = *(const uint4*)(tb + (o11 + po));
            f2v p00[4], p01[4], p10[4], p11[4];
            unpack8p(r00, p00); unpack8p(r01, p01);
            unpack8p(r10, p10); unpack8p(r11, p11);
#pragma unroll
            for (int i = 0; i < 4; ++i) {
                f2v a = af[pp * 4 + i];
                a = __builtin_elementwise_fma(v00, p00[i], a);
                a = __builtin_elementwise_fma(v01, p01[i], a);
                a = __builtin_elementwise_fma(v10, p10[i], a);
                a = __builtin_elementwise_fma(v11, p11[i], a);
                af[pp * 4 + i] = a;
            }
        }
    }
    // reduce the four z-quarters (lane bits 4 and 5)
#pragma unroll
    for (int i = 0; i < 16; ++i) {
        af[i].x += __shfl_xor(af[i].x, 16);
        af[i].y += __shfl_xor(af[i].y, 16);
        af[i].x += __shfl_xor(af[i].x, 32);
        af[i].y += __shfl_xor(af[i].y, 32);
    }

    if (h == 0) {
        const float s = 1.0f / 48.0f;
        size_t pbase = ((size_t)vb * Hn + y) * NCI8 + g * 4;
#pragma unroll
        for (int pp = 0; pp < 4; ++pp) {
            unsigned short o[8];
#pragma unroll
            for (int j = 0; j < 8; ++j) {
                f2v a = af[pp * 4 + (j >> 1)];
                o[j] = f2bf(((j & 1) ? a.y : a.x) * s);
            }
            size_t off = (pbase + pp) * Wn + x;
            *(uint4*)(&featP[off * 8]) = pack8(o);
        }
    }
}

// ---------------------------------------------------------------------------
// K2: bilinear resize 48->96 from bf16 featP into zero-padded packetized rz.
// Extra 219 blocks zero the rz halo (replaces the 22 MB memset).
// ---------------------------------------------------------------------------
__global__ __launch_bounds__(256) void k_resize(const unsigned short* __restrict__ featP,
                                                unsigned short* __restrict__ rz) {
    if (blockIdx.x >= 5184) {
        int hid = (blockIdx.x - 5184) * 256 + threadIdx.x;
        if (hid >= 55872) return;              // 12 vb * 12 c8 * 388 border pkts
        int p = hid % 388;
        int r2 = hid / 388;
        int c8 = r2 % NCI8;
        int vb = r2 / NCI8;
        int py, px;
        if (p < 98)      { py = 0;  px = p; }
        else if (p < 196){ py = 97; px = p - 98; }
        else { int q = p - 196; py = 1 + (q >> 1); px = (q & 1) ? 97 : 0; }
        size_t off = (((size_t)vb * PD + py) * NCI8 + c8) * PD + px;
        *(uint4*)(&rz[off * 8]) = (uint4){0u, 0u, 0u, 0u};
        return;
    }
    int idx = blockIdx.x * 256 + threadIdx.x;   // 1,327,104 total
    int x = idx % TWn;
    int r = idx / TWn;
    int c8i = r % NCI8; r /= NCI8;
    int y = r % THn;
    int vb = r / THn;

    float sy = fmaxf(0.5f * (y + 0.5f) - 0.5f, 0.0f);
    int y0 = min((int)sy, Hn - 1);
    int y1 = min(y0 + 1, Hn - 1);
    float ty = sy - (float)y0;
    float sx = fmaxf(0.5f * (x + 0.5f) - 0.5f, 0.0f);
    int x0 = min((int)sx, Wn - 1);
    int x1 = min(x0 + 1, Wn - 1);
    float tx = sx - (float)x0;

    const unsigned short* fb = featP + ((size_t)vb * Hn * NCI8 + c8i) * Wn * 8;
    const unsigned short* r0 = fb + (size_t)y0 * (NCI8 * Wn * 8);
    const unsigned short* r1 = fb + (size_t)y1 * (NCI8 * Wn * 8);
    uint4 q00 = *(const uint4*)(r0 + (size_t)x0 * 8);
    uint4 q01 = *(const uint4*)(r0 + (size_t)x1 * 8);
    uint4 q10 = *(const uint4*)(r1 + (size_t)x0 * 8);
    uint4 q11 = *(const uint4*)(r1 + (size_t)x1 * 8);
    float f00[8], f01[8], f10[8], f11[8];
    unpack8(q00, f00); unpack8(q01, f01); unpack8(q10, f10); unpack8(q11, f11);

    float w00 = (1.f - ty) * (1.f - tx), w01 = (1.f - ty) * tx;
    float w10 = ty * (1.f - tx),         w11 = ty * tx;

    unsigned short o[8];
#pragma unroll
    for (int j = 0; j < 8; ++j)
        o[j] = f2bf(w00 * f00[j] + w01 * f01[j] + w10 * f10[j] + w11 * f11[j]);

    size_t off = (((size_t)vb * PD + (y + 1)) * NCI8 + c8i) * PD + (x + 1);
    *(uint4*)(&rz[off * 8]) = pack8(o);
}

// ---------------------------------------------------------------------------
// K3: conv1 3x3 SAME, implicit GEMM bf16 MFMA 16x16x32 + FUSED BN PARTIALS.
// Wave = 32 n (2 tiles) x 48 co -> 1728 blocks. Epilogue shfl-reduces the
// fp32 accumulators (pre-rounding) to per-block channel sum/sumsq -> part2.
// ---------------------------------------------------------------------------
__global__ __launch_bounds__(256) void k_conv1(const unsigned short* __restrict__ rz,
                                               const unsigned short* __restrict__ wAtP,
                                               unsigned short* __restrict__ co1,
                                               float* __restrict__ part2) {
    __shared__ float sS[4][48];
    __shared__ float sQ[4][48];

    int blk = blockIdx.x;
    int n0 = blk * 64;                 // 9216 % 64 == 0 -> single vb
    int vb = n0 / 9216;
    int nl0 = n0 - vb * 9216;

    int t = threadIdx.x;
    int wv = t >> 6;
    int ch = wv & 1;                   // co half (0..1)
    int ns = wv >> 1;                  // n subtile (0..1)
    int l = t & 63;
    int l15 = l & 15, q = l >> 4;

    int nt0 = nl0 + ns * 32;
    int nl[2];
    const unsigned short* pB[2];
#pragma unroll
    for (int i = 0; i < 2; ++i) {
        nl[i] = nt0 + i * 16 + l15;
        int y = nl[i] / 96, x = nl[i] - y * 96;
        pB[i] = rz + ((((size_t)vb * PD + y) * NCI8) * PD + x) * 8;
    }

    f4v acc[2][3];
#pragma unroll
    for (int i = 0; i < 2; ++i)
#pragma unroll
        for (int mt = 0; mt < 3; ++mt) acc[i][mt] = (f4v){0.f, 0.f, 0.f, 0.f};

#pragma unroll
    for (int ks = 0; ks < 3; ++ks) {
        int ci8 = ks * 4 + q;
        const unsigned short* pb0 = pB[0] + (size_t)ci8 * (PD * 8);
        const unsigned short* pb1 = pB[1] + (size_t)ci8 * (PD * 8);
        const unsigned short* pa = wAtP + ((size_t)ci8 * 96 + ch * 48 + l15) * 8;
#pragma unroll
        for (int tap = 0; tap < 9; ++tap) {
            int dy = tap / 3, dx = tap % 3;
            size_t toff = ((size_t)dy * (NCI8 * PD) + dx) * 8;   // const
            s8v b0 = *(const s8v*)(pb0 + toff);
            s8v b1 = *(const s8v*)(pb1 + toff);
            const unsigned short* ap = pa + (size_t)tap * (NCI8 * 96 * 8);
#pragma unroll
            for (int mt = 0; mt < 3; ++mt) {
                s8v a = *(const s8v*)(ap + (size_t)mt * (16 * 8));
                acc[0][mt] = __builtin_amdgcn_mfma_f32_16x16x32_bf16(a, b0, acc[0][mt], 0, 0, 0);
                acc[1][mt] = __builtin_amdgcn_mfma_f32_16x16x32_bf16(a, b1, acc[1][mt], 0, 0, 0);
            }
        }
    }

#pragma unroll
    for (int i = 0; i < 2; ++i) {
#pragma unroll
        for (int mt = 0; mt < 3; ++mt) {
            int co0 = ch * 48 + mt * 16 + q * 4;   // D: row(m)=q*4+reg, col(n)=l15
            ushort4 pk;
            pk.x = f2bf(acc[i][mt][0]); pk.y = f2bf(acc[i][mt][1]);
            pk.z = f2bf(acc[i][mt][2]); pk.w = f2bf(acc[i][mt][3]);
            size_t off = (((size_t)vb * NCI8 + (co0 >> 3)) * 9216 + nl[i]) * 8 + (co0 & 7);
            *(ushort4*)(&co1[off]) = pk;
        }
    }

    // ---- fused BN partials: reduce over the 32 n this wave owns ----
#pragma unroll
    for (int mt = 0; mt < 3; ++mt) {
#pragma unroll
        for (int reg = 0; reg < 4; ++reg) {
            float a0 = acc[0][mt][reg], a1 = acc[1][mt][reg];
            float xs = a0 + a1;
            float xq = a0 * a0 + a1 * a1;
#pragma unroll
            for (int off = 1; off < 16; off <<= 1) {
                xs += __shfl_xor(xs, off);
                xq += __shfl_xor(xq, off);
            }
            if (l15 == 0) {
                sS[wv][mt * 16 + q * 4 + reg] = xs;
                sQ[wv][mt * 16 + q * 4 + reg] = xq;
            }
        }
    }
    __syncthreads();
    if (t < 96) {                       // co = t = ch*48 + cl
        int c2 = t / 48, cl = t % 48;   // waves wv = c2 and c2+2 share this co
        part2[(size_t)blk * 192 + t]      = sS[c2][cl] + sS[c2 + 2][cl];
        part2[(size_t)blk * 192 + 96 + t] = sQ[c2][cl] + sQ[c2 + 2][cl];
    }
}

// ---------------------------------------------------------------------------
// K4: stats finalize. 6 blocks (one per view): reduce 288 block-partials
// (2 b x 144 chunks) per channel -> scale/shift. 1.33 MB total reads.
// ---------------------------------------------------------------------------
__global__ __launch_bounds__(256) void k_statsR(const float* __restrict__ part2,
                                                const float* __restrict__ gamma,
                                                const float* __restrict__ beta,
                                                float* __restrict__ scale,
                                                float* __restrict__ shift) {
    __shared__ float red[192];
    int v = blockIdx.x;
    int t = threadIdx.x;
    if (t < 192) {
        float a = 0.f;
#pragma unroll 2
        for (int bb = 0; bb < 2; ++bb) {
            const float* p = part2 + ((size_t)(v * 2 + bb) * 144) * 192 + t;
            for (int c = 0; c < 144; ++c) a += p[(size_t)c * 192];
        }
        red[t] = a;
    }
    __syncthreads();
    if (t < 96) {
        float S = red[t], Q = red[96 + t];
        const float invN = 1.0f / (float)(Bn * THn * TWn);
        float mu = S * invN;
        float var = Q * invN - mu * mu;
        float rstd = rsqrtf(fmaxf(var, 0.0f) + EPSf);
        float sc = rstd * gamma[t];
        scale[v * 96 + t] = sc;
        shift[v * 96 + t] = beta[t] - mu * sc;
    }
}

// ---------------------------------------------------------------------------
// K5: fused BN + exact GELU + conv2 1x1 MFMA + bias -> out fp32.
// Epilogue stages the 96x64 tile in LDS (+1 pad) and writes full 256B rows.
// ---------------------------------------------------------------------------
__global__ __launch_bounds__(256) void k_conv2(const unsigned short* __restrict__ co1,
                                               const unsigned short* __restrict__ wCP,
                                               const float* __restrict__ scale,
                                               const float* __restrict__ shift,
                                               const float* __restrict__ b2,
                                               float* __restrict__ out) {
    __shared__ float ssc[96], ssh[96], sbias[96];
    __shared__ float sOut[96 * 65];    // [co][n_local], +1 pad per row

    int blk = blockIdx.x;
    int n0 = blk * 64;
    int vb = n0 / 9216;
    int nl0 = n0 - vb * 9216;
    int v = vb >> 1, b = vb & 1;

    int t = threadIdx.x;
    int wv = t >> 6;
    int l = t & 63;
    int l15 = l & 15, q = l >> 4;

    if (t < 96) {
        ssc[t] = scale[v * 96 + t];
        ssh[t] = shift[v * 96 + t];
        sbias[t] = b2[t];
    }
    __syncthreads();

    int n = nl0 + wv * 16 + l15;

    f4v acc[6];
#pragma unroll
    for (int mt = 0; mt < 6; ++mt) acc[mt] = (f4v){0.f, 0.f, 0.f, 0.f};

#pragma unroll
    for (int ks = 0; ks < 3; ++ks) {
        int ci8 = ks * 4 + q;
        int ci0 = ci8 * 8;
        float sc[8], sh[8];
#pragma unroll
        for (int j = 0; j < 8; ++j) { sc[j] = ssc[ci0 + j]; sh[j] = ssh[ci0 + j]; }

        const unsigned short* pb = co1 + (((size_t)vb * NCI8 + ci8) * 9216 + n) * 8;
        uint4 raw = *(const uint4*)pb;
        float f[8];
        unpack8(raw, f);
        unsigned short o[8];
#pragma unroll
        for (int j = 0; j < 8; ++j) {
            float yv = f[j] * sc[j] + sh[j];
            o[j] = f2bf(gelu_f(yv));
        }
        s8v bfr = __builtin_bit_cast(s8v, pack8(o));

        const unsigned short* pa = wCP + ((size_t)ci8 * 96 + l15) * 8;
#pragma unroll
        for (int mt = 0; mt < 6; ++mt) {
            s8v a = *(const s8v*)(pa + (size_t)mt * (16 * 8));
            acc[mt] = __builtin_amdgcn_mfma_f32_16x16x32_bf16(a, bfr, acc[mt], 0, 0, 0);
        }
    }

    // stage (+bias) into LDS, then write full 256B rows
    int nloc = wv * 16 + l15;
#pragma unroll
    for (int mt = 0; mt < 6; ++mt) {
        int co0 = mt * 16 + q * 4;
#pragma unroll
        for (int reg = 0; reg < 4; ++reg) {
            int co = co0 + reg;
            sOut[co * 65 + nloc] = acc[mt][reg] + sbias[co];
        }
    }
    __syncthreads();

    size_t obase = ((size_t)(b * Vn + v) * Cn) * 9216 + nl0;
#pragma unroll
    for (int r = 0; r < 6; ++r) {
        int cid = r * 256 + t;             // 0..1535
        int row = cid >> 4;                // co
        int chunk = cid & 15;              // 4-float chunk within the 64-n row
        float4 vv = *(const float4*)(&sOut[row * 65 + chunk * 4]);
        *(float4*)(&out[obase + (size_t)row * 9216 + chunk * 4]) = vv;
    }
}

// ---------------------------------------------------------------------------
extern "C" void kernel_launch(void* const* d_in, const int* in_sizes, int n_in,
                              void* d_out, int out_size, void* d_ws, size_t ws_size,
                              hipStream_t stream) {
    const float* tokens = (const float*)d_in[0];
    const float* angles = (const float*)d_in[1];
    const float* w1     = (const float*)d_in[2];
    const float* gamma  = (const float*)d_in[3];
    const float* beta   = (const float*)d_in[4];
    const float* w2     = (const float*)d_in[5];
    const float* b2     = (const float*)d_in[6];
    float* out = (float*)d_out;

    // workspace layout (bytes) — temporal aliasing discipline:
    //  ws+0         : featP 5,308,416 bf16 (live k_feat10..k_resize);
    //                 part2 1,327,104 fp32 reuses ws+0 after featP dead (k_conv1+)
    //  ws+5,308,416 : tokB 42,467,328 (live k_pre..k_feat10);
    //                 rz 22,127,616 aliases its head (written k_resize, after tokB dead)
    //  ws+27,436,032: co1 21,233,664 (written k_conv1, after tokB dead)
    //  ws+48,669,696: wAtP 165,888 | ws+48,835,584: wCP 18,432
    //  ws+48,854,016: scale 2,304  | ws+48,856,320: shift 2,304
    char* ws = (char*)d_ws;
    unsigned short* featP = (unsigned short*)(ws);
    float* part2          = (float*)(ws);
    unsigned short* tokB  = (unsigned short*)(ws + 5308416);
    unsigned short* rz    = (unsigned short*)(ws + 5308416);
    unsigned short* co1   = (unsigned short*)(ws + 27436032);
    unsigned short* wAtP  = (unsigned short*)(ws + 48669696);
    unsigned short* wCP   = (unsigned short*)(ws + 48835584);
    float* scale = (float*)(ws + 48854016);
    float* shift = (float*)(ws + 48856320);

    k_pre<<<10728, 256, 0, stream>>>(tokens, tokB, w1, w2, wAtP, wCP);
    k_feat10<<<1296, 256, 0, stream>>>(tokB, angles, featP);
    k_resize<<<5403, 256, 0, stream>>>(featP, rz);      // tokB dead; rz interior + halo
    k_conv1<<<1728, 256, 0, stream>>>(rz, wAtP, co1, part2);  // featP dead; part2 at ws+0
    k_statsR<<<6, 256, 0, stream>>>(part2, gamma, beta, scale, shift);
    k_conv2<<<1728, 256, 0, stream>>>(co1, wCP, scale, shift, b2, out);
}

// Round 12
// 256.072 us; speedup vs baseline: 1.1168x; 1.1168x over previous
//
#include <hip/hip_runtime.h>
#include <math.h>

// Problem constants
#define Bn 2
#define Vn 6
#define Cn 96
#define Dn 48
#define Hn 48
#define Wn 48
#define THn 96
#define TWn 96
#define EPSf 1e-5f

// packetized geometry: 16B packets of 8 consecutive ci
#define PD 98
#define NCI8 12
// rz:  (((vb*PD+py)*NCI8 + ci8)*PD + px)*8 + e     (bf16, zero-padded halo)
// co1: (((vb*NCI8+co8)*9216 + n)*8 + e             (bf16)
// wAtP:(((tap*NCI8+ci8)*96 + co)*8 + e             (bf16)
// wCP: ((ci8*96 + co)*8 + e                        (bf16)

typedef __attribute__((ext_vector_type(8))) short s8v;   // 8 bf16
typedef __attribute__((ext_vector_type(4))) float f4v;   // MFMA acc
typedef __attribute__((ext_vector_type(2))) float f2v;   // packed fp32 pair

__device__ __forceinline__ unsigned short f2bf(float f) {
    unsigned int u = __builtin_bit_cast(unsigned int, f);
    u += 0x7FFFu + ((u >> 16) & 1u);          // RNE
    return (unsigned short)(u >> 16);
}
__device__ __forceinline__ float bf2f(unsigned short h) {
    unsigned int u = ((unsigned int)h) << 16;
    return __builtin_bit_cast(float, u);
}
__device__ __forceinline__ void unpack8(uint4 r, float* f) {
    unsigned int w[4] = {r.x, r.y, r.z, r.w};
#pragma unroll
    for (int j = 0; j < 8; ++j)
        f[j] = bf2f((unsigned short)((w[j >> 1] >> ((j & 1) * 16)) & 0xFFFFu));
}
// unpack a 16B packet into 4 float2 pairs: pair i = channels (2i, 2i+1)
__device__ __forceinline__ void unpack8p(uint4 r, f2v* p) {
    unsigned int w[4] = {r.x, r.y, r.z, r.w};
#pragma unroll
    for (int i = 0; i < 4; ++i) {
        f2v t;
        t.x = __builtin_bit_cast(float, w[i] << 16);
        t.y = __builtin_bit_cast(float, w[i] & 0xFFFF0000u);
        p[i] = t;
    }
}
__device__ __forceinline__ uint4 pack8(const unsigned short* o) {
    uint4 pk;
    pk.x = (unsigned int)o[0] | ((unsigned int)o[1] << 16);
    pk.y = (unsigned int)o[2] | ((unsigned int)o[3] << 16);
    pk.z = (unsigned int)o[4] | ((unsigned int)o[5] << 16);
    pk.w = (unsigned int)o[6] | ((unsigned int)o[7] << 16);
    return pk;
}

// Branchless exact-GELU: erf via Abramowitz-Stegun 7.1.26 (|err| < 1.5e-7).
__device__ __forceinline__ float gelu_f(float y) {
    float z = y * 0.70710678118654752f;
    float a = fabsf(z);
    float t = __builtin_amdgcn_rcpf(fmaf(0.3275911f, a, 1.0f));
    float e = __builtin_amdgcn_exp2f(-1.4426950408889634f * a * a);
    float p = t * fmaf(t, fmaf(t, fmaf(t, fmaf(t, 1.061405429f,
                                               -1.453152027f),
                                       1.421413741f),
                               -0.284496736f),
                       0.254829592f);
    float er = fmaf(-p, e, 1.0f);            // erf(|z|)
    er = copysignf(er, z);
    return 0.5f * y * (1.0f + er);
}

// ---------------------------------------------------------------------------
// K0: merged tokens fp32->bf16 + weight prep. blk<10368: tok; else weights.
// ---------------------------------------------------------------------------
__global__ __launch_bounds__(256) void k_pre(const float* __restrict__ tokens,
                                             unsigned short* __restrict__ tokB,
                                             const float* __restrict__ w1,
                                             const float* __restrict__ w2,
                                             unsigned short* __restrict__ wAtP,
                                             unsigned short* __restrict__ wCP) {
    if (blockIdx.x < 10368) {
        int idx = blockIdx.x * 256 + threadIdx.x;      // 2,654,208 threads
        size_t base = (size_t)idx * 8;
        float4 f0 = *(const float4*)(tokens + base);
        float4 f1 = *(const float4*)(tokens + base + 4);
        unsigned short o[8] = {f2bf(f0.x), f2bf(f0.y), f2bf(f0.z), f2bf(f0.w),
                               f2bf(f1.x), f2bf(f1.y), f2bf(f1.z), f2bf(f1.w)};
        *(uint4*)(&tokB[base]) = pack8(o);
    } else {
        int i = (blockIdx.x - 10368) * 256 + threadIdx.x;
        if (i < 82944) {                       // 9*12*96*8
            int e = i & 7;
            int u = i >> 3;
            int co = u % 96;
            int u2 = u / 96;                   // tap*12 + ci8
            int ci8 = u2 % NCI8;
            int tap = u2 / NCI8;
            wAtP[i] = f2bf(w1[(co * 96 + ci8 * 8 + e) * 9 + tap]);
        } else if (i < 92160) {
            int j = i - 82944;
            int e = j & 7;
            int u = j >> 3;
            int co = u % 96;
            int ci8 = u / 96;
            wCP[j] = f2bf(w2[co * 96 + ci8 * 8 + e]);
        }
    }
}

// ---------------------------------------------------------------------------
// K1: projection; z split across wave QUARTERS (lane bits 4-5); (b,y)-major
// + XCD-chunked swizzle. Geometry INLINE. Proven 52.2 us @ VALUBusy 80%
// (round 10); both widening (r11) and LDS staging (r8) regressed — this is
// the validated configuration for this kernel.
// ---------------------------------------------------------------------------
__global__ __launch_bounds__(256) void k_feat9(const unsigned short* __restrict__ tokB,
                                               const float* __restrict__ angles,
                                               unsigned short* __restrict__ featP) {
    int gid = blockIdx.x;
    int xcd = gid & 7;
    int pos = gid >> 3;
    int vblk = xcd * 648 + pos;            // virtual block, (b,y)-major order
    int group = vblk / 9;                  // (b*48 + y)*6 + v
    int inner = vblk - group * 9;
    int v = group % 6;
    int by = group / 6;
    int y = by % 48;
    int b = by / 48;
    int vb = v * 2 + b;

    int t = threadIdx.x;
    int l = t & 63;
    int h = l >> 4;                        // z-quarter 0..3
    int s0 = inner * 64 + (t >> 6) * 16 + (l & 15);   // site in (v,b,y): 0..575
    int c8 = s0 % NCI8;
    int x = s0 / NCI8;

    float th = angles[v];
    float ct = cosf(th), st = sinf(th);
    float xr = (float)x + 0.5f - 24.0f;
    float xterm = ct * xr + 23.5f;         // ix = st*zr + xterm
    float zterm = -st * xr + 23.5f;        // iz = ct*zr + zterm

    const char* tb = (const char*)tokB +
                     ((size_t)b * 10616832 + (size_t)y * 4608 + c8 * 8) * 2;

    f2v af[4];
#pragma unroll
    for (int i = 0; i < 4; ++i) af[i] = (f2v){0.f, 0.f};

#pragma unroll 4
    for (int k = 0; k < 12; ++k) {
        float zr = (float)(h * 12 + k) + 0.5f - 24.0f;
        float ix = fmaf(st, zr, xterm);
        float iz = fmaf(ct, zr, zterm);
        float x0f = floorf(ix), z0f = floorf(iz);
        float tx = ix - x0f, tz = iz - z0f;
        int x0 = (int)x0f, z0 = (int)z0f;
        float wx0 = (1.f - tx) * (((x0 >= 0) && (x0 < 48)) ? 1.f : 0.f);
        float wx1 = tx * (((x0 >= -1) && (x0 < 47)) ? 1.f : 0.f);
        float wz0 = (1.f - tz) * (((z0 >= 0) && (z0 < 48)) ? 1.f : 0.f);
        float wz1 = tz * (((z0 >= -1) && (z0 < 47)) ? 1.f : 0.f);
        int xi0 = min(max(x0, 0), 47), xi1 = min(max(x0 + 1, 0), 47);
        int zi0 = min(max(z0, 0), 47), zi1 = min(max(z0 + 1, 0), 47);
        int r0o = zi0 * 442368, r1o = zi1 * 442368;   // byte row offsets
        int c0o = xi0 * 192,    c1o = xi1 * 192;      // byte col offsets

        uint4 r00 = *(const uint4*)(tb + (r0o + c0o));
        uint4 r01 = *(const uint4*)(tb + (r0o + c1o));
        uint4 r10 = *(const uint4*)(tb + (r1o + c0o));
        uint4 r11 = *(const uint4*)(tb + (r1o + c1o));
        f2v p00[4], p01[4], p10[4], p11[4];
        unpack8p(r00, p00); unpack8p(r01, p01);
        unpack8p(r10, p10); unpack8p(r11, p11);
        float w00 = wz0 * wx0, w01 = wz0 * wx1;
        float w10 = wz1 * wx0, w11 = wz1 * wx1;
        f2v v00 = (f2v){w00, w00}, v01 = (f2v){w01, w01};
        f2v v10 = (f2v){w10, w10}, v11 = (f2v){w11, w11};
#pragma unroll
        for (int i = 0; i < 4; ++i) {
            af[i] = __builtin_elementwise_fma(v00, p00[i], af[i]);
            af[i] = __builtin_elementwise_fma(v01, p01[i], af[i]);
            af[i] = __builtin_elementwise_fma(v10, p10[i], af[i]);
            af[i] = __builtin_elementwise_fma(v11, p11[i], af[i]);
        }
    }
    // reduce the four z-quarters (lane bits 4 and 5)
#pragma unroll
    for (int i = 0; i < 4; ++i) {
        af[i].x += __shfl_xor(af[i].x, 16);
        af[i].y += __shfl_xor(af[i].y, 16);
        af[i].x += __shfl_xor(af[i].x, 32);
        af[i].y += __shfl_xor(af[i].y, 32);
    }

    if (h == 0) {
        const float s = 1.0f / 48.0f;
        unsigned short o[8];
#pragma unroll
        for (int j = 0; j < 8; ++j)
            o[j] = f2bf(((j & 1) ? af[j >> 1].y : af[j >> 1].x) * s);
        size_t off = (((size_t)vb * Hn + y) * NCI8 + c8) * Wn + x;
        *(uint4*)(&featP[off * 8]) = pack8(o);
    }
}

// ---------------------------------------------------------------------------
// K2: bilinear resize 48->96 from bf16 featP into zero-padded packetized rz.
// Extra 219 blocks zero the rz halo (replaces the 22 MB memset).
// ---------------------------------------------------------------------------
__global__ __launch_bounds__(256) void k_resize(const unsigned short* __restrict__ featP,
                                                unsigned short* __restrict__ rz) {
    if (blockIdx.x >= 5184) {
        int hid = (blockIdx.x - 5184) * 256 + threadIdx.x;
        if (hid >= 55872) return;              // 12 vb * 12 c8 * 388 border pkts
        int p = hid % 388;
        int r2 = hid / 388;
        int c8 = r2 % NCI8;
        int vb = r2 / NCI8;
        int py, px;
        if (p < 98)      { py = 0;  px = p; }
        else if (p < 196){ py = 97; px = p - 98; }
        else { int q = p - 196; py = 1 + (q >> 1); px = (q & 1) ? 97 : 0; }
        size_t off = (((size_t)vb * PD + py) * NCI8 + c8) * PD + px;
        *(uint4*)(&rz[off * 8]) = (uint4){0u, 0u, 0u, 0u};
        return;
    }
    int idx = blockIdx.x * 256 + threadIdx.x;   // 1,327,104 total
    int x = idx % TWn;
    int r = idx / TWn;
    int c8i = r % NCI8; r /= NCI8;
    int y = r % THn;
    int vb = r / THn;

    float sy = fmaxf(0.5f * (y + 0.5f) - 0.5f, 0.0f);
    int y0 = min((int)sy, Hn - 1);
    int y1 = min(y0 + 1, Hn - 1);
    float ty = sy - (float)y0;
    float sx = fmaxf(0.5f * (x + 0.5f) - 0.5f, 0.0f);
    int x0 = min((int)sx, Wn - 1);
    int x1 = min(x0 + 1, Wn - 1);
    float tx = sx - (float)x0;

    const unsigned short* fb = featP + ((size_t)vb * Hn * NCI8 + c8i) * Wn * 8;
    const unsigned short* r0 = fb + (size_t)y0 * (NCI8 * Wn * 8);
    const unsigned short* r1 = fb + (size_t)y1 * (NCI8 * Wn * 8);
    uint4 q00 = *(const uint4*)(r0 + (size_t)x0 * 8);
    uint4 q01 = *(const uint4*)(r0 + (size_t)x1 * 8);
    uint4 q10 = *(const uint4*)(r1 + (size_t)x0 * 8);
    uint4 q11 = *(const uint4*)(r1 + (size_t)x1 * 8);
    float f00[8], f01[8], f10[8], f11[8];
    unpack8(q00, f00); unpack8(q01, f01); unpack8(q10, f10); unpack8(q11, f11);

    float w00 = (1.f - ty) * (1.f - tx), w01 = (1.f - ty) * tx;
    float w10 = ty * (1.f - tx),         w11 = ty * tx;

    unsigned short o[8];
#pragma unroll
    for (int j = 0; j < 8; ++j)
        o[j] = f2bf(w00 * f00[j] + w01 * f01[j] + w10 * f10[j] + w11 * f11[j]);

    size_t off = (((size_t)vb * PD + (y + 1)) * NCI8 + c8i) * PD + (x + 1);
    *(uint4*)(&rz[off * 8]) = pack8(o);
}

// ---------------------------------------------------------------------------
// K3: conv1 3x3 SAME, implicit GEMM bf16 MFMA 16x16x32 + FUSED BN PARTIALS.
// Wave = 32 n (2 tiles) x 48 co -> 1728 blocks, XCD-CHUNKED (1728%8==0,
// bijective): each XCD gets 216 consecutive blocks (~1.5 vb of rz, 2.7 MB,
// L2-resident; dy taps re-read each rz row 3x -> halo rows stay local).
// Epilogue shfl-reduces fp32 accumulators to per-block sum/sumsq -> part2.
// ---------------------------------------------------------------------------
__global__ __launch_bounds__(256) void k_conv1(const unsigned short* __restrict__ rz,
                                               const unsigned short* __restrict__ wAtP,
                                               unsigned short* __restrict__ co1,
                                               float* __restrict__ part2) {
    __shared__ float sS[4][48];
    __shared__ float sQ[4][48];

    int blk = (blockIdx.x & 7) * 216 + (blockIdx.x >> 3);   // XCD-chunked
    int n0 = blk * 64;                 // 9216 % 64 == 0 -> single vb
    int vb = n0 / 9216;
    int nl0 = n0 - vb * 9216;

    int t = threadIdx.x;
    int wv = t >> 6;
    int ch = wv & 1;                   // co half (0..1)
    int ns = wv >> 1;                  // n subtile (0..1)
    int l = t & 63;
    int l15 = l & 15, q = l >> 4;

    int nt0 = nl0 + ns * 32;
    int nl[2];
    const unsigned short* pB[2];
#pragma unroll
    for (int i = 0; i < 2; ++i) {
        nl[i] = nt0 + i * 16 + l15;
        int y = nl[i] / 96, x = nl[i] - y * 96;
        pB[i] = rz + ((((size_t)vb * PD + y) * NCI8) * PD + x) * 8;
    }

    f4v acc[2][3];
#pragma unroll
    for (int i = 0; i < 2; ++i)
#pragma unroll
        for (int mt = 0; mt < 3; ++mt) acc[i][mt] = (f4v){0.f, 0.f, 0.f, 0.f};

#pragma unroll
    for (int ks = 0; ks < 3; ++ks) {
        int ci8 = ks * 4 + q;
        const unsigned short* pb0 = pB[0] + (size_t)ci8 * (PD * 8);
        const unsigned short* pb1 = pB[1] + (size_t)ci8 * (PD * 8);
        const unsigned short* pa = wAtP + ((size_t)ci8 * 96 + ch * 48 + l15) * 8;
#pragma unroll
        for (int tap = 0; tap < 9; ++tap) {
            int dy = tap / 3, dx = tap % 3;
            size_t toff = ((size_t)dy * (NCI8 * PD) + dx) * 8;   // const
            s8v b0 = *(const s8v*)(pb0 + toff);
            s8v b1 = *(const s8v*)(pb1 + toff);
            const unsigned short* ap = pa + (size_t)tap * (NCI8 * 96 * 8);
#pragma unroll
            for (int mt = 0; mt < 3; ++mt) {
                s8v a = *(const s8v*)(ap + (size_t)mt * (16 * 8));
                acc[0][mt] = __builtin_amdgcn_mfma_f32_16x16x32_bf16(a, b0, acc[0][mt], 0, 0, 0);
                acc[1][mt] = __builtin_amdgcn_mfma_f32_16x16x32_bf16(a, b1, acc[1][mt], 0, 0, 0);
            }
        }
    }

#pragma unroll
    for (int i = 0; i < 2; ++i) {
#pragma unroll
        for (int mt = 0; mt < 3; ++mt) {
            int co0 = ch * 48 + mt * 16 + q * 4;   // D: row(m)=q*4+reg, col(n)=l15
            ushort4 pk;
            pk.x = f2bf(acc[i][mt][0]); pk.y = f2bf(acc[i][mt][1]);
            pk.z = f2bf(acc[i][mt][2]); pk.w = f2bf(acc[i][mt][3]);
            size_t off = (((size_t)vb * NCI8 + (co0 >> 3)) * 9216 + nl[i]) * 8 + (co0 & 7);
            *(ushort4*)(&co1[off]) = pk;
        }
    }

    // ---- fused BN partials: reduce over the 32 n this wave owns ----
#pragma unroll
    for (int mt = 0; mt < 3; ++mt) {
#pragma unroll
        for (int reg = 0; reg < 4; ++reg) {
            float a0 = acc[0][mt][reg], a1 = acc[1][mt][reg];
            float xs = a0 + a1;
            float xq = a0 * a0 + a1 * a1;
#pragma unroll
            for (int off = 1; off < 16; off <<= 1) {
                xs += __shfl_xor(xs, off);
                xq += __shfl_xor(xq, off);
            }
            if (l15 == 0) {
                sS[wv][mt * 16 + q * 4 + reg] = xs;
                sQ[wv][mt * 16 + q * 4 + reg] = xq;
            }
        }
    }
    __syncthreads();
    if (t < 96) {                       // co = t = ch*48 + cl
        int c2 = t / 48, cl = t % 48;   // waves wv = c2 and c2+2 share this co
        part2[(size_t)blk * 192 + t]      = sS[c2][cl] + sS[c2 + 2][cl];
        part2[(size_t)blk * 192 + 96 + t] = sQ[c2][cl] + sQ[c2 + 2][cl];
    }
}

// ---------------------------------------------------------------------------
// K4: stats finalize. 6 blocks (one per view): reduce 288 block-partials
// (2 b x 144 chunks) per channel -> scale/shift. 1.33 MB total reads.
// ---------------------------------------------------------------------------
__global__ __launch_bounds__(256) void k_statsR(const float* __restrict__ part2,
                                                const float* __restrict__ gamma,
                                                const float* __restrict__ beta,
                                                float* __restrict__ scale,
                                                float* __restrict__ shift) {
    __shared__ float red[192];
    int v = blockIdx.x;
    int t = threadIdx.x;
    if (t < 192) {
        float a = 0.f;
#pragma unroll 2
        for (int bb = 0; bb < 2; ++bb) {
            const float* p = part2 + ((size_t)(v * 2 + bb) * 144) * 192 + t;
            for (int c = 0; c < 144; ++c) a += p[(size_t)c * 192];
        }
        red[t] = a;
    }
    __syncthreads();
    if (t < 96) {
        float S = red[t], Q = red[96 + t];
        const float invN = 1.0f / (float)(Bn * THn * TWn);
        float mu = S * invN;
        float var = Q * invN - mu * mu;
        float rstd = rsqrtf(fmaxf(var, 0.0f) + EPSf);
        float sc = rstd * gamma[t];
        scale[v * 96 + t] = sc;
        shift[v * 96 + t] = beta[t] - mu * sc;
    }
}

// ---------------------------------------------------------------------------
// K5: fused BN + exact GELU + conv2 1x1 MFMA + bias -> out fp32.
// Epilogue stages the 96x64 tile in LDS (+1 pad) and writes full 256B rows.
// ---------------------------------------------------------------------------
__global__ __launch_bounds__(256) void k_conv2(const unsigned short* __restrict__ co1,
                                               const unsigned short* __restrict__ wCP,
                                               const float* __restrict__ scale,
                                               const float* __restrict__ shift,
                                               const float* __restrict__ b2,
                                               float* __restrict__ out) {
    __shared__ float ssc[96], ssh[96], sbias[96];
    __shared__ float sOut[96 * 65];    // [co][n_local], +1 pad per row

    int blk = blockIdx.x;
    int n0 = blk * 64;
    int vb = n0 / 9216;
    int nl0 = n0 - vb * 9216;
    int v = vb >> 1, b = vb & 1;

    int t = threadIdx.x;
    int wv = t >> 6;
    int l = t & 63;
    int l15 = l & 15, q = l >> 4;

    if (t < 96) {
        ssc[t] = scale[v * 96 + t];
        ssh[t] = shift[v * 96 + t];
        sbias[t] = b2[t];
    }
    __syncthreads();

    int n = nl0 + wv * 16 + l15;

    f4v acc[6];
#pragma unroll
    for (int mt = 0; mt < 6; ++mt) acc[mt] = (f4v){0.f, 0.f, 0.f, 0.f};

#pragma unroll
    for (int ks = 0; ks < 3; ++ks) {
        int ci8 = ks * 4 + q;
        int ci0 = ci8 * 8;
        float sc[8], sh[8];
#pragma unroll
        for (int j = 0; j < 8; ++j) { sc[j] = ssc[ci0 + j]; sh[j] = ssh[ci0 + j]; }

        const unsigned short* pb = co1 + (((size_t)vb * NCI8 + ci8) * 9216 + n) * 8;
        uint4 raw = *(const uint4*)pb;
        float f[8];
        unpack8(raw, f);
        unsigned short o[8];
#pragma unroll
        for (int j = 0; j < 8; ++j) {
            float yv = f[j] * sc[j] + sh[j];
            o[j] = f2bf(gelu_f(yv));
        }
        s8v bfr = __builtin_bit_cast(s8v, pack8(o));

        const unsigned short* pa = wCP + ((size_t)ci8 * 96 + l15) * 8;
#pragma unroll
        for (int mt = 0; mt < 6; ++mt) {
            s8v a = *(const s8v*)(pa + (size_t)mt * (16 * 8));
            acc[mt] = __builtin_amdgcn_mfma_f32_16x16x32_bf16(a, bfr, acc[mt], 0, 0, 0);
        }
    }

    // stage (+bias) into LDS, then write full 256B rows
    int nloc = wv * 16 + l15;
#pragma unroll
    for (int mt = 0; mt < 6; ++mt) {
        int co0 = mt * 16 + q * 4;
#pragma unroll
        for (int reg = 0; reg < 4; ++reg) {
            int co = co0 + reg;
            sOut[co * 65 + nloc] = acc[mt][reg] + sbias[co];
        }
    }
    __syncthreads();

    size_t obase = ((size_t)(b * Vn + v) * Cn) * 9216 + nl0;
#pragma unroll
    for (int r = 0; r < 6; ++r) {
        int cid = r * 256 + t;             // 0..1535
        int row = cid >> 4;                // co
        int chunk = cid & 15;              // 4-float chunk within the 64-n row
        float4 vv = *(const float4*)(&sOut[row * 65 + chunk * 4]);
        *(float4*)(&out[obase + (size_t)row * 9216 + chunk * 4]) = vv;
    }
}

// ---------------------------------------------------------------------------
extern "C" void kernel_launch(void* const* d_in, const int* in_sizes, int n_in,
                              void* d_out, int out_size, void* d_ws, size_t ws_size,
                              hipStream_t stream) {
    const float* tokens = (const float*)d_in[0];
    const float* angles = (const float*)d_in[1];
    const float* w1     = (const float*)d_in[2];
    const float* gamma  = (const float*)d_in[3];
    const float* beta   = (const float*)d_in[4];
    const float* w2     = (const float*)d_in[5];
    const float* b2     = (const float*)d_in[6];
    float* out = (float*)d_out;

    // workspace layout (bytes) — temporal aliasing discipline:
    //  ws+0         : featP 5,308,416 bf16 (live k_feat9..k_resize);
    //                 part2 1,327,104 fp32 reuses ws+0 after featP dead (k_conv1+)
    //  ws+5,308,416 : tokB 42,467,328 (live k_pre..k_feat9);
    //                 rz 22,127,616 aliases its head (written k_resize, after tokB dead)
    //  ws+27,436,032: co1 21,233,664 (written k_conv1, after tokB dead)
    //  ws+48,669,696: wAtP 165,888 | ws+48,835,584: wCP 18,432
    //  ws+48,854,016: scale 2,304  | ws+48,856,320: shift 2,304
    char* ws = (char*)d_ws;
    unsigned short* featP = (unsigned short*)(ws);
    float* part2          = (float*)(ws);
    unsigned short* tokB  = (unsigned short*)(ws + 5308416);
    unsigned short* rz    = (unsigned short*)(ws + 5308416);
    unsigned short* co1   = (unsigned short*)(ws + 27436032);
    unsigned short* wAtP  = (unsigned short*)(ws + 48669696);
    unsigned short* wCP   = (unsigned short*)(ws + 48835584);
    float* scale = (float*)(ws + 48854016);
    float* shift = (float*)(ws + 48856320);

    k_pre<<<10728, 256, 0, stream>>>(tokens, tokB, w1, w2, wAtP, wCP);
    k_feat9<<<5184, 256, 0, stream>>>(tokB, angles, featP);
    k_resize<<<5403, 256, 0, stream>>>(featP, rz);      // tokB dead; rz interior + halo
    k_conv1<<<1728, 256, 0, stream>>>(rz, wAtP, co1, part2);  // featP dead; part2 at ws+0
    k_statsR<<<6, 256, 0, stream>>>(part2, gamma, beta, scale, shift);
    k_conv2<<<1728, 256, 0, stream>>>(co1, wCP, scale, shift, b2, out);
}